// Round 12
// baseline (242.952 us; speedup 1.0000x reference)
//
#include <hip/hip_runtime.h>
#include <math.h>

constexpr int NN  = 50000;   // nodes
constexpr int NE  = 150000;  // edges
constexpr int NIN = 16;      // node features in
constexpr int EIN = 19;      // edge features in
constexpr int HD  = 32;      // hidden H
constexpr int NTILES = NE / 16;  // 9375
constexpr int NBLK_E = 128;
constexpr int NBLK_X = 64;

#define LEAK  0.1f
#define BNEPS 1e-5f

typedef __attribute__((ext_vector_type(8))) short bfrag;
typedef __attribute__((ext_vector_type(4))) float f32x4;
typedef __attribute__((ext_vector_type(2))) float f32x2;
typedef __attribute__((ext_vector_type(4))) int   i32x4;

__device__ __forceinline__ float lky(float v){ return fmaxf(v, LEAK*v); }
__device__ __forceinline__ unsigned f2bf(float f){
  unsigned u = __float_as_uint(f);
  return ((u + 0x7FFFu + ((u >> 16) & 1u)) >> 16);   // RNE
}
__device__ __forceinline__ void split8(const float* v, i32x4& h4, i32x4& l4){
  unsigned hs[8], ls[8];
  #pragma unroll
  for(int j = 0; j < 8; j++){
    unsigned hh = f2bf(v[j]);
    float hf = __uint_as_float(hh << 16);
    hs[j] = hh; ls[j] = f2bf(v[j] - hf);
  }
  h4[0] = (int)(hs[0] | (hs[1]<<16)); h4[1] = (int)(hs[2] | (hs[3]<<16));
  h4[2] = (int)(hs[4] | (hs[5]<<16)); h4[3] = (int)(hs[6] | (hs[7]<<16));
  l4[0] = (int)(ls[0] | (ls[1]<<16)); l4[1] = (int)(ls[2] | (ls[3]<<16));
  l4[2] = (int)(ls[4] | (ls[5]<<16)); l4[3] = (int)(ls[6] | (ls[7]<<16));
}

// ---------------------------------------------------------------- zero
__global__ void zero_kernel(float* __restrict__ p, int n){
  int stride = gridDim.x * blockDim.x;
  for(int i = blockIdx.x*blockDim.x + threadIdx.x; i < n; i += stride) p[i] = 0.f;
}

// ---------------------------------------------------------------- stats (proven R5)
__global__ __launch_bounds__(256) void stats_all_kernel(const float* __restrict__ e,
                                                        const float* __restrict__ x,
                                                        float* __restrict__ partial_e,
                                                        float* __restrict__ partial_x){
  __shared__ float red[4][40];
  const int tid = threadIdx.x, lane = tid & 63, wid = tid >> 6;
  if(blockIdx.x < NBLK_E){
    float s[EIN], q[EIN];
    #pragma unroll
    for(int c = 0; c < EIN; c++){ s[c] = 0.f; q[c] = 0.f; }
    const int gstride = NBLK_E * 256;
    for(int g = blockIdx.x*256 + tid; g < NE/4; g += gstride){
      const f32x4* p = (const f32x4*)(e + (size_t)g * 76);
      #pragma unroll
      for(int m = 0; m < 19; m++){
        f32x4 v = p[m];
        #pragma unroll
        for(int j = 0; j < 4; j++){
          int c = (4*m + j) % 19;
          s[c] += v[j]; q[c] = fmaf(v[j], v[j], q[c]);
        }
      }
    }
    #pragma unroll
    for(int off = 32; off; off >>= 1){
      #pragma unroll
      for(int c = 0; c < EIN; c++){ s[c] += __shfl_xor(s[c], off); q[c] += __shfl_xor(q[c], off); }
    }
    if(lane == 0){
      #pragma unroll
      for(int c = 0; c < EIN; c++){ red[wid][c] = s[c]; red[wid][20 + c] = q[c]; }
    }
    __syncthreads();
    if(tid < 39 && tid != 19)
      partial_e[blockIdx.x*40 + tid] = red[0][tid] + red[1][tid] + red[2][tid] + red[3][tid];
  } else {
    float s[NIN], q[NIN];
    #pragma unroll
    for(int c = 0; c < NIN; c++){ s[c] = 0.f; q[c] = 0.f; }
    const int bid = blockIdx.x - NBLK_E;
    const int gstride = NBLK_X * 256;
    for(int r = bid*256 + tid; r < NN; r += gstride){
      const f32x4* p = (const f32x4*)(x + (size_t)r * NIN);
      #pragma unroll
      for(int m = 0; m < 4; m++){
        f32x4 v = p[m];
        #pragma unroll
        for(int j = 0; j < 4; j++){
          int c = 4*m + j;
          s[c] += v[j]; q[c] = fmaf(v[j], v[j], q[c]);
        }
      }
    }
    #pragma unroll
    for(int off = 32; off; off >>= 1){
      #pragma unroll
      for(int c = 0; c < NIN; c++){ s[c] += __shfl_xor(s[c], off); q[c] += __shfl_xor(q[c], off); }
    }
    if(lane == 0){
      #pragma unroll
      for(int c = 0; c < NIN; c++){ red[wid][c] = s[c]; red[wid][16 + c] = q[c]; }
    }
    __syncthreads();
    if(tid < 32)
      partial_x[bid*32 + tid] = red[0][tid] + red[1][tid] + red[2][tid] + red[3][tid];
  }
}

// ---------------------------------------------------------------- prep (proven R5)
__global__ __launch_bounds__(1024) void prep_kernel(const float* __restrict__ partial_e,
                                                    const float* __restrict__ partial_x,
                                                    const float* __restrict__ ge, const float* __restrict__ be,
                                                    const float* __restrict__ gx, const float* __restrict__ bx,
                                                    const float* __restrict__ l0W1, const float* __restrict__ l0b1,
                                                    const float* __restrict__ l1W1, const float* __restrict__ l1b1,
                                                    const float* __restrict__ l2W1, const float* __restrict__ l2b1,
                                                    const float* __restrict__ emW1, const float* __restrict__ emb1,
                                                    const float* __restrict__ emW2, const float* __restrict__ emb2,
                                                    const float* __restrict__ nm1W1, const float* __restrict__ nm1b1,
                                                    const float* __restrict__ nm1W2, const float* __restrict__ nm1b2,
                                                    float* __restrict__ ss_g, float* __restrict__ W1f,
                                                    float* __restrict__ b1f, float* __restrict__ biasP,
                                                    short* __restrict__ predpk){
  __shared__ float ss[70];
  __shared__ float emW1f[608];
  __shared__ float emb1f[32];
  __shared__ float predW[7168];
  const int t = threadIdx.x;

  if(t < EIN){
    float s = 0.f, q = 0.f;
    for(int b = 0; b < NBLK_E; b++){ s += partial_e[b*40 + t]; q += partial_e[b*40 + 20 + t]; }
    float m = s / (float)NE;
    float v = q / (float)NE - m*m;
    float sc = ge[t] * rsqrtf(v + BNEPS);
    ss[t] = sc; ss[EIN + t] = be[t] - m*sc;
  } else if(t >= 32 && t < 32 + NIN){
    int c = t - 32;
    float s = 0.f, q = 0.f;
    for(int b = 0; b < NBLK_X; b++){ s += partial_x[b*32 + c]; q += partial_x[b*32 + 16 + c]; }
    float m = s / (float)NN;
    float v = q / (float)NN - m*m;
    float sc = gx[c] * rsqrtf(v + BNEPS);
    ss[2*EIN + c] = sc; ss[2*EIN + NIN + c] = bx[c] - m*sc;
  }
  __syncthreads();
  if(t < 70) ss_g[t] = ss[t];

  if(t < 128){
    int seg = t >> 5, j = t & 31;
    if(seg == 0){
      if(j < NIN){
        float acc = l0b1[j];
        for(int k = 0; k < EIN; k++){
          W1f[0*640 + k*NIN + j] = ss[k] * l0W1[k*NIN + j];
          acc += ss[EIN+k] * l0W1[k*NIN + j];
        }
        b1f[0*32 + j] = acc;
      }
    } else if(seg == 1){
      float acc = l1b1[j];
      for(int k = 0; k < EIN; k++){
        W1f[1*640 + k*HD + j] = ss[k] * l1W1[k*HD + j];
        acc += ss[EIN+k] * l1W1[k*HD + j];
      }
      b1f[1*32 + j] = acc;
    } else if(seg == 2){
      float acc = l2b1[j];
      for(int k = 0; k < EIN; k++){
        W1f[2*640 + k*HD + j] = ss[k] * l2W1[k*HD + j];
        acc += ss[EIN+k] * l2W1[k*HD + j];
      }
      b1f[2*32 + j] = acc;
    } else {
      float acc = emb1[j];
      for(int k = 0; k < EIN; k++){
        emW1f[k*HD + j] = ss[k] * emW1[(2*HD+k)*HD + j];
        acc += ss[EIN+k] * emW1[(2*HD+k)*HD + j];
      }
      emb1f[j] = acc;
    }
  }
  __syncthreads();

  for(int i = t; i < 224*32; i += 1024){
    int k = i >> 5, n = i & 31;
    float v;
    if(k < 64)       v = emW1[k*32 + n];
    else if(k < 83)  v = emW1f[(k-64)*32 + n];
    else if(k < 96)  v = 0.f;
    else if(k < 128) v = emW2[(k-96)*32 + n];
    else if(k < 192) v = nm1W1[(k-128)*32 + n];
    else             v = nm1W2[(k-192)*32 + n];
    predW[i] = v;
  }
  if(t < 128){
    int s = t >> 5, n = t & 31;
    biasP[t] = (s==0) ? emb1f[n] : (s==1) ? emb2[n] : (s==2) ? nm1b1[n] : nm1b2[n];
  }
  __syncthreads();

  for(int idx = t; idx < 14*512; idx += 1024){
    int c = idx >> 9, l = (idx >> 3) & 63, j = idx & 7;
    int kbg = c >> 1, nc = c & 1;
    int k = kbg*32 + 8*(l>>4) + j;
    int n = nc*16 + (l & 15);
    predpk[idx] = (short)f2bf(predW[k*32 + n]);
  }
}

// ---------------------------------------------------------------- pack all three W2
__global__ __launch_bounds__(256) void w2pack_all_kernel(const float* __restrict__ W20,
                                                         const float* __restrict__ W21,
                                                         const float* __restrict__ W22,
                                                         short* __restrict__ w2pk){
  int idx = blockIdx.x*256 + threadIdx.x;
  if(idx >= 81920) return;
  const float* W2; int DIN, base, ci;
  if(idx < 16384){ W2 = W20; DIN = 16; base = 0;     ci = idx; }
  else if(idx < 49152){ W2 = W21; DIN = 32; base = 32768; ci = idx - 16384; }
  else { W2 = W22; DIN = 32; base = 65536; ci = idx - 49152; }
  int c = ci >> 9, l = (ci >> 3) & 63, j = ci & 7;
  int k = 8*(l>>4) + j;
  int n = c*16 + (l & 15);
  float v = (k < DIN) ? W2[(size_t)k*(DIN*HD) + n] : 0.f;
  w2pk[base + ci] = (short)f2bf(v);
}

// ---------------------------------------------------------------- rootn: BN-normalize(x) in regs + layer0 root GEMV
__global__ __launch_bounds__(256) void rootn_kernel(const float* __restrict__ x,
                                                    const float* __restrict__ ssx,
                                                    const float* __restrict__ root,
                                                    const float* __restrict__ bias,
                                                    float* __restrict__ x_a){
  __shared__ float rs[NIN*HD];
  __shared__ float scs[NIN], shs[NIN], bs[HD];
  const int tid = threadIdx.x;
  for(int i = tid; i < NIN*HD; i += 256) rs[i] = root[i];
  if(tid < NIN){ scs[tid] = ssx[tid]; shs[tid] = ssx[NIN + tid]; }
  else if(tid < NIN + HD) bs[tid - NIN] = bias[tid - NIN];
  __syncthreads();

  int n = blockIdx.x*256 + tid;
  if(n >= NN) return;
  float xb[NIN];
  const f32x4* xp = (const f32x4*)(x + (size_t)n*NIN);
  #pragma unroll
  for(int g = 0; g < 4; g++){
    f32x4 v = xp[g];
    #pragma unroll
    for(int j = 0; j < 4; j++) xb[g*4+j] = fmaf(v[j], scs[g*4+j], shs[g*4+j]);
  }
  f32x4 a0 = *(const f32x4*)&bs[0],  a1 = *(const f32x4*)&bs[4];
  f32x4 a2 = *(const f32x4*)&bs[8],  a3 = *(const f32x4*)&bs[12];
  f32x4 a4 = *(const f32x4*)&bs[16], a5 = *(const f32x4*)&bs[20];
  f32x4 a6 = *(const f32x4*)&bs[24], a7 = *(const f32x4*)&bs[28];
  #pragma unroll
  for(int k = 0; k < NIN; k++){
    float v = xb[k];
    const f32x4* wp = (const f32x4*)&rs[k*HD];
    f32x4 vv = {v,v,v,v};
    a0 = __builtin_elementwise_fma(vv, wp[0], a0);
    a1 = __builtin_elementwise_fma(vv, wp[1], a1);
    a2 = __builtin_elementwise_fma(vv, wp[2], a2);
    a3 = __builtin_elementwise_fma(vv, wp[3], a3);
    a4 = __builtin_elementwise_fma(vv, wp[4], a4);
    a5 = __builtin_elementwise_fma(vv, wp[5], a5);
    a6 = __builtin_elementwise_fma(vv, wp[6], a6);
    a7 = __builtin_elementwise_fma(vv, wp[7], a7);
  }
  f32x4* outp = (f32x4*)(x_a + (size_t)n*HD);
  outp[0]=a0; outp[1]=a1; outp[2]=a2; outp[3]=a3;
  outp[4]=a4; outp[5]=a5; outp[6]=a6; outp[7]=a7;
}

// ---------------------------------------------------------------- T1 for ALL layers in one pass over e
__global__ __launch_bounds__(256) void t1all_kernel(const float* __restrict__ eraw,
                                                    const float* __restrict__ W1f,
                                                    const float* __restrict__ b1f,
                                                    short* __restrict__ T10,
                                                    short* __restrict__ T11,
                                                    short* __restrict__ T12){
  int e = blockIdx.x*256 + threadIdx.x;
  if(e >= NE) return;
  const float* ep = eraw + (size_t)e*EIN;
  float eb[EIN];
  #pragma unroll
  for(int k = 0; k < EIN; k++) eb[k] = ep[k];

  {
    float tv[16];
    #pragma unroll
    for(int j = 0; j < 16; j++) tv[j] = b1f[j];
    #pragma unroll
    for(int k = 0; k < EIN; k++){
      float v = eb[k];
      #pragma unroll
      for(int j = 0; j < 16; j++) tv[j] = fmaf(v, W1f[k*16 + j], tv[j]);
    }
    unsigned pk[8];
    #pragma unroll
    for(int p = 0; p < 8; p++){
      float a = tv[2*p], b = tv[2*p+1];
      pk[p] = f2bf(fmaxf(a, LEAK*a)) | (f2bf(fmaxf(b, LEAK*b)) << 16);
    }
    i32x4* outp = (i32x4*)(T10 + (size_t)e*32);
    i32x4 v0; v0[0]=(int)pk[0]; v0[1]=(int)pk[1]; v0[2]=(int)pk[2]; v0[3]=(int)pk[3];
    i32x4 v1; v1[0]=(int)pk[4]; v1[1]=(int)pk[5]; v1[2]=(int)pk[6]; v1[3]=(int)pk[7];
    i32x4 zz; zz[0]=0; zz[1]=0; zz[2]=0; zz[3]=0;
    outp[0] = v0; outp[1] = v1; outp[2] = zz; outp[3] = zz;
  }
  #pragma unroll
  for(int l = 1; l < 3; l++){
    const float* Wl = W1f + l*640;
    const float* bl = b1f + l*32;
    short* Tl = (l == 1) ? T11 : T12;
    float tv[32];
    #pragma unroll
    for(int j = 0; j < 32; j++) tv[j] = bl[j];
    #pragma unroll
    for(int k = 0; k < EIN; k++){
      float v = eb[k];
      #pragma unroll
      for(int j = 0; j < 32; j++) tv[j] = fmaf(v, Wl[k*32 + j], tv[j]);
    }
    unsigned pk[16];
    #pragma unroll
    for(int p = 0; p < 16; p++){
      float a = tv[2*p], b = tv[2*p+1];
      pk[p] = f2bf(fmaxf(a, LEAK*a)) | (f2bf(fmaxf(b, LEAK*b)) << 16);
    }
    i32x4* outp = (i32x4*)(Tl + (size_t)e*32);
    #pragma unroll
    for(int g = 0; g < 4; g++){
      i32x4 v; v[0]=(int)pk[g*4]; v[1]=(int)pk[g*4+1]; v[2]=(int)pk[g*4+2]; v[3]=(int)pk[g*4+3];
      outp[g] = v;
    }
  }
}

// ---------------------------------------------------------------- root (layers 1,2)
template<int DIN>
__global__ __launch_bounds__(256) void rootv2_kernel(const float* __restrict__ xin,
                                                     const float* __restrict__ root,
                                                     const float* __restrict__ bias,
                                                     float* __restrict__ xout){
  int n = blockIdx.x*256 + threadIdx.x;
  if(n >= NN) return;
  float xr[DIN];
  const f32x4* xp = (const f32x4*)(xin + (size_t)n*DIN);
  #pragma unroll
  for(int g = 0; g < DIN/4; g++){ f32x4 v = xp[g];
    #pragma unroll
    for(int j = 0; j < 4; j++) xr[g*4+j] = v[j]; }
  float acc[HD];
  #pragma unroll
  for(int o = 0; o < HD; o++) acc[o] = bias[o];
  #pragma unroll
  for(int k = 0; k < DIN; k++){
    float v = xr[k];
    #pragma unroll
    for(int o = 0; o < HD; o++) acc[o] = fmaf(v, root[k*HD + o], acc[o]);
  }
  f32x4* outp = (f32x4*)(xout + (size_t)n*HD);
  #pragma unroll
  for(int g = 0; g < 8; g++){ f32x4 v; v[0]=acc[g*4]; v[1]=acc[g*4+1]; v[2]=acc[g*4+2]; v[3]=acc[g*4+3]; outp[g] = v; }
}

// ---------------------------------------------------------------- msg v8: W2 half in VGPRs per parity wave, ZERO barriers in tile loop
// wave = (tile, parity): computes o in [parity*16, parity*16+16). Weights: NCHP = NCH/2
// B-frag chunks (even/odd) resident in VGPRs, amortized over TPW tiles.
template<int DIN, int NCH, int TPW, int NORM>
__global__ __launch_bounds__(256, 1) void msg8_kernel(const short* __restrict__ T1,
                                                      const int* __restrict__ rowp,
                                                      const int* __restrict__ colp,
                                                      const float* __restrict__ xin,
                                                      const float* __restrict__ ssx,
                                                      const short* __restrict__ w2p,
                                                      const float* __restrict__ b2,
                                                      float* __restrict__ xout){
  constexpr int NCHP = NCH / 2;
  __shared__ float b2s[NCH*16];
  __shared__ float xgs[4][DIN][16];     // per-wave private, transposed [i][edge]

  const int tid = threadIdx.x;
  const int l   = tid & 63;
  const int wid = tid >> 6;             // 0..3
  const int grp = l >> 4, lo16 = l & 15;
  const int pair   = wid >> 1;          // tile-slot within block
  const int parity = wid & 1;           // output half / chunk parity

  // stage b2 (once per block)
  for(int t = tid; t < NCH*16; t += 256) b2s[t] = b2[t];

  // W2 half-chunks resident in VGPRs: wb[i] = chunk (2i+parity)
  bfrag wb[NCHP];
  #pragma unroll
  for(int i = 0; i < NCHP; i++)
    wb[i] = *(const bfrag*)(w2p + ((size_t)(2*i + parity)*64 + l)*8);
  __syncthreads();   // b2s ready (only barrier in the kernel)

  const int tbase = (blockIdx.x*2 + pair) * TPW;

  for(int tt = 0; tt < TPW; tt++){
    const int tile = tbase + tt;
    if(tile >= NTILES) break;
    const int e0 = tile * 16;

    // stage x rows transposed into private region (in-wave write->read, no barrier)
    {
      int r = rowp[e0 + lo16];
      if(DIN == 32){
        const f32x4* xp = (const f32x4*)(xin + (size_t)r*32 + grp*8);
        f32x4 a = xp[0], b = xp[1];
        #pragma unroll
        for(int j = 0; j < 4; j++) xgs[wid][grp*8 + j][lo16]     = a[j];
        #pragma unroll
        for(int j = 0; j < 4; j++) xgs[wid][grp*8 + 4 + j][lo16] = b[j];
      } else {
        const f32x4* xp = (const f32x4*)(xin + (size_t)r*16 + grp*4);
        f32x4 a = xp[0];
        if(NORM){
          f32x4 sc = *(const f32x4*)(ssx + grp*4);
          f32x4 sh = *(const f32x4*)(ssx + NIN + grp*4);
          a = __builtin_elementwise_fma(a, sc, sh);
        }
        #pragma unroll
        for(int j = 0; j < 4; j++) xgs[wid][grp*4 + j][lo16] = a[j];
      }
    }

    bfrag af = *(const bfrag*)(T1 + (size_t)(e0 + lo16)*32 + grp*8);

    f32x2 ma = {0.f, 0.f}, mb = {0.f, 0.f};

    #pragma unroll
    for(int i = 0; i < NCHP; i++){
      float bv = b2s[(2*i + parity)*16 + lo16];
      f32x4 c = {bv, bv, bv, bv};
      f32x4 u = __builtin_amdgcn_mfma_f32_16x16x32_bf16(af, wb[i], c, 0, 0, 0);
      f32x4 xv = *(const f32x4*)&xgs[wid][i][grp*4];
      f32x2 xva = {xv[0], xv[1]}, xvb = {xv[2], xv[3]};
      f32x2 ua = {u[0], u[1]}, ub = {u[2], u[3]};
      f32x2 la = __builtin_elementwise_max(ua, ua*LEAK);
      f32x2 lb = __builtin_elementwise_max(ub, ub*LEAK);
      ma = __builtin_elementwise_fma(xva, la, ma);
      mb = __builtin_elementwise_fma(xvb, lb, mb);
    }

    float m[4] = {ma[0], ma[1], mb[0], mb[1]};
    #pragma unroll
    for(int reg = 0; reg < 4; reg++){
      int ce = colp[e0 + grp*4 + reg];
      atomicAdd(&xout[(size_t)ce*HD + parity*16 + lo16], m[reg]);
    }
  }
}

// ---------------------------------------------------------------- predictor v6 (proven R10/R11: TPW=2)
__global__ __launch_bounds__(256, 4) void pred6_kernel(const float* __restrict__ x,
                                                       const float* __restrict__ eraw,
                                                       const int* __restrict__ rowp,
                                                       const int* __restrict__ colp,
                                                       const short* __restrict__ predpk,
                                                       const float* __restrict__ biasP,
                                                       float* __restrict__ agg,
                                                       float* __restrict__ cnt){
  __shared__ short fAhi[4][16][104];
  __shared__ short fAlo[4][16][104];
  __shared__ short uAhi[4][16][40];
  __shared__ short uAlo[4][16][40];

  const int tid = threadIdx.x;
  const int l = tid & 63, wid = tid >> 6;
  const int grp = l >> 4, lo16 = l & 15;

  bfrag wb[14];
  #pragma unroll
  for(int c = 0; c < 14; c++) wb[c] = *(const bfrag*)(predpk + ((size_t)c*64 + l)*8);
  float bP[8];
  #pragma unroll
  for(int s = 0; s < 4; s++){
    bP[s*2]   = biasP[s*32 + lo16];
    bP[s*2+1] = biasP[s*32 + 16 + lo16];
  }

  f32x4 z; z[0]=0.f; z[1]=0.f; z[2]=0.f; z[3]=0.f;
  const int tbase = (blockIdx.x*4 + wid) * 2;

  for(int tt = 0; tt < 2; tt++){
    const int tile = tbase + tt;
    if(tile >= NTILES) break;
    const int e0 = tile * 16;

    {
      float v[8];
      i32x4 h4, l4;
      int r = rowp[e0 + lo16];
      const float* xp = x + (size_t)r*32 + grp*8;
      #pragma unroll
      for(int j = 0; j < 8; j++) v[j] = xp[j];
      split8(v, h4, l4);
      *(i32x4*)&fAhi[wid][lo16][grp*8] = h4;
      *(i32x4*)&fAlo[wid][lo16][grp*8] = l4;

      int c = colp[e0 + lo16];
      const float* xq = x + (size_t)c*32 + grp*8;
      #pragma unroll
      for(int j = 0; j < 8; j++) v[j] = xq[j];
      split8(v, h4, l4);
      *(i32x4*)&fAhi[wid][lo16][32 + grp*8] = h4;
      *(i32x4*)&fAlo[wid][lo16][32 + grp*8] = l4;

      const float* ep = eraw + (size_t)(e0 + lo16)*EIN;
      #pragma unroll
      for(int j = 0; j < 8; j++){ int f = grp*8 + j; v[j] = (f < EIN) ? ep[f] : 0.f; }
      split8(v, h4, l4);
      *(i32x4*)&fAhi[wid][lo16][64 + grp*8] = h4;
      *(i32x4*)&fAlo[wid][lo16][64 + grp*8] = l4;
    }

    #pragma unroll
    for(int nc = 0; nc < 2; nc++){
      f32x4 acc = z;
      #pragma unroll
      for(int kb = 0; kb < 3; kb++){
        bfrag ah = *(const bfrag*)&fAhi[wid][lo16][kb*32 + grp*8];
        bfrag al = *(const bfrag*)&fAlo[wid][lo16][kb*32 + grp*8];
        acc = __builtin_amdgcn_mfma_f32_16x16x32_bf16(ah, wb[kb*2 + nc], acc, 0, 0, 0);
        acc = __builtin_amdgcn_mfma_f32_16x16x32_bf16(al, wb[kb*2 + nc], acc, 0, 0, 0);
      }
      int n = nc*16 + lo16;
      float bv = bP[nc];
      #pragma unroll
      for(int reg = 0; reg < 4; reg++){
        float uv = acc[reg] + bv; uv = fmaxf(uv, LEAK*uv);
        unsigned hh = f2bf(uv);
        float hf = __uint_as_float(hh << 16);
        uAhi[wid][grp*4 + reg][n] = (short)hh;
        uAlo[wid][grp*4 + reg][n] = (short)f2bf(uv - hf);
      }
    }

    #pragma unroll
    for(int nc = 0; nc < 2; nc++){
      f32x4 acc = z;
      bfrag ah = *(const bfrag*)&uAhi[wid][lo16][grp*8];
      bfrag al = *(const bfrag*)&uAlo[wid][lo16][grp*8];
      acc = __builtin_amdgcn_mfma_f32_16x16x32_bf16(ah, wb[6 + nc], acc, 0, 0, 0);
      acc = __builtin_amdgcn_mfma_f32_16x16x32_bf16(al, wb[6 + nc], acc, 0, 0, 0);
      int n = nc*16 + lo16;
      float bv = bP[2 + nc];
      #pragma unroll
      for(int reg = 0; reg < 4; reg++){
        float ev = acc[reg] + bv;
        unsigned hh = f2bf(ev);
        float hf = __uint_as_float(hh << 16);
        fAhi[wid][grp*4 + reg][32 + n] = (short)hh;
        fAlo[wid][grp*4 + reg][32 + n] = (short)f2bf(ev - hf);
      }
    }

    #pragma unroll
    for(int nc = 0; nc < 2; nc++){
      f32x4 acc = z;
      #pragma unroll
      for(int kb = 0; kb < 2; kb++){
        bfrag ah = *(const bfrag*)&fAhi[wid][lo16][kb*32 + grp*8];
        bfrag al = *(const bfrag*)&fAlo[wid][lo16][kb*32 + grp*8];
        acc = __builtin_amdgcn_mfma_f32_16x16x32_bf16(ah, wb[8 + kb*2 + nc], acc, 0, 0, 0);
        acc = __builtin_amdgcn_mfma_f32_16x16x32_bf16(al, wb[8 + kb*2 + nc], acc, 0, 0, 0);
      }
      int n = nc*16 + lo16;
      float bv = bP[4 + nc];
      #pragma unroll
      for(int reg = 0; reg < 4; reg++){
        float vv = acc[reg] + bv; vv = fmaxf(vv, LEAK*vv);
        unsigned hh = f2bf(vv);
        float hf = __uint_as_float(hh << 16);
        uAhi[wid][grp*4 + reg][n] = (short)hh;
        uAlo[wid][grp*4 + reg][n] = (short)f2bf(vv - hf);
      }
    }

    int ce[4];
    #pragma unroll
    for(int reg = 0; reg < 4; reg++) ce[reg] = colp[e0 + grp*4 + reg];

    #pragma unroll
    for(int nc = 0; nc < 2; nc++){
      f32x4 acc = z;
      bfrag ah = *(const bfrag*)&uAhi[wid][lo16][grp*8];
      bfrag al = *(const bfrag*)&uAlo[wid][lo16][grp*8];
      acc = __builtin_amdgcn_mfma_f32_16x16x32_bf16(ah, wb[12 + nc], acc, 0, 0, 0);
      acc = __builtin_amdgcn_mfma_f32_16x16x32_bf16(al, wb[12 + nc], acc, 0, 0, 0);
      int n = nc*16 + lo16;
      float bv = bP[6 + nc];
      #pragma unroll
      for(int reg = 0; reg < 4; reg++)
        atomicAdd(&agg[(size_t)ce[reg]*HD + n], acc[reg] + bv);
    }

    if(l < 16) atomicAdd(&cnt[colp[e0 + l]], 1.f);
  }
}

// ---------------------------------------------------------------- final v2 (proven R8)
__global__ __launch_bounds__(256) void final2_kernel(const float* __restrict__ x,
                                                     const float* __restrict__ agg,
                                                     const float* __restrict__ cnt,
                                                     const float* __restrict__ W1,
                                                     const float* __restrict__ b1,
                                                     const float* __restrict__ W2,
                                                     const float* __restrict__ b2,
                                                     float* __restrict__ out){
  __shared__ float w1s[2*HD*HD];
  __shared__ float w2s[HD*2];
  __shared__ float b1s[HD];
  __shared__ float b2s[2];
  const int tid = threadIdx.x;
  for(int i = tid; i < 2*HD*HD; i += 256) w1s[i] = W1[i];
  if(tid < 64) w2s[tid] = W2[tid];
  if(tid < HD) b1s[tid] = b1[tid];
  if(tid < 2)  b2s[tid] = b2[tid];
  __syncthreads();

  int n = blockIdx.x*256 + tid;
  if(n >= NN) return;
  float inv = 1.f / fmaxf(cnt[n], 1.f);

  float xin[HD], ain[HD];
  const f32x4* xp = (const f32x4*)(x + (size_t)n*HD);
  const f32x4* ap = (const f32x4*)(agg + (size_t)n*HD);
  #pragma unroll
  for(int g = 0; g < 8; g++){
    f32x4 v = xp[g];
    #pragma unroll
    for(int j = 0; j < 4; j++) xin[g*4+j] = v[j];
  }
  #pragma unroll
  for(int g = 0; g < 8; g++){
    f32x4 v = ap[g];
    #pragma unroll
    for(int j = 0; j < 4; j++) ain[g*4+j] = v[j] * inv;
  }

  f32x4 a0 = *(const f32x4*)&b1s[0],  a1 = *(const f32x4*)&b1s[4];
  f32x4 a2 = *(const f32x4*)&b1s[8],  a3 = *(const f32x4*)&b1s[12];
  f32x4 a4 = *(const f32x4*)&b1s[16], a5 = *(const f32x4*)&b1s[20];
  f32x4 a6 = *(const f32x4*)&b1s[24], a7 = *(const f32x4*)&b1s[28];
  #pragma unroll
  for(int k = 0; k < HD; k++){
    float v = xin[k];
    const f32x4* wp = (const f32x4*)&w1s[k*HD];
    f32x4 vv = {v,v,v,v};
    a0 = __builtin_elementwise_fma(vv, wp[0], a0);
    a1 = __builtin_elementwise_fma(vv, wp[1], a1);
    a2 = __builtin_elementwise_fma(vv, wp[2], a2);
    a3 = __builtin_elementwise_fma(vv, wp[3], a3);
    a4 = __builtin_elementwise_fma(vv, wp[4], a4);
    a5 = __builtin_elementwise_fma(vv, wp[5], a5);
    a6 = __builtin_elementwise_fma(vv, wp[6], a6);
    a7 = __builtin_elementwise_fma(vv, wp[7], a7);
  }
  #pragma unroll
  for(int k = 0; k < HD; k++){
    float v = ain[k];
    const f32x4* wp = (const f32x4*)&w1s[(HD+k)*HD];
    f32x4 vv = {v,v,v,v};
    a0 = __builtin_elementwise_fma(vv, wp[0], a0);
    a1 = __builtin_elementwise_fma(vv, wp[1], a1);
    a2 = __builtin_elementwise_fma(vv, wp[2], a2);
    a3 = __builtin_elementwise_fma(vv, wp[3], a3);
    a4 = __builtin_elementwise_fma(vv, wp[4], a4);
    a5 = __builtin_elementwise_fma(vv, wp[5], a5);
    a6 = __builtin_elementwise_fma(vv, wp[6], a6);
    a7 = __builtin_elementwise_fma(vv, wp[7], a7);
  }

  float t[HD];
  *(f32x4*)&t[0]  = a0; *(f32x4*)&t[4]  = a1; *(f32x4*)&t[8]  = a2; *(f32x4*)&t[12] = a3;
  *(f32x4*)&t[16] = a4; *(f32x4*)&t[20] = a5; *(f32x4*)&t[24] = a6; *(f32x4*)&t[28] = a7;

  float o0 = b2s[0], o1 = b2s[1];
  #pragma unroll
  for(int k = 0; k < HD; k++){
    float v = lky(t[k]);
    o0 = fmaf(v, w2s[k*2],   o0);
    o1 = fmaf(v, w2s[k*2+1], o1);
  }

  float m  = fmaxf(o0, o1);
  float ls = m + logf(expf(o0 - m) + expf(o1 - m));
  out[(size_t)n*2]   = o0 - ls;
  out[(size_t)n*2+1] = o1 - ls;
}

// ---------------------------------------------------------------- launch
extern "C" void kernel_launch(void* const* d_in, const int* in_sizes, int n_in,
                              void* d_out, int out_size, void* d_ws, size_t ws_size,
                              hipStream_t stream){
  const float* x  = (const float*)d_in[0];
  const int*   ei = (const int*)  d_in[1];
  const float* e  = (const float*)d_in[2];
  const float* bn_node_g = (const float*)d_in[4];
  const float* bn_node_b = (const float*)d_in[5];
  const float* bn_edge_g = (const float*)d_in[6];
  const float* bn_edge_b = (const float*)d_in[7];
  const float* lW1[3], *lb1[3], *lW2[3], *lb2[3], *lroot[3], *lbias[3];
  for(int l = 0; l < 3; l++){
    lW1[l]   = (const float*)d_in[8 + 6*l + 0];
    lb1[l]   = (const float*)d_in[8 + 6*l + 1];
    lW2[l]   = (const float*)d_in[8 + 6*l + 2];
    lb2[l]   = (const float*)d_in[8 + 6*l + 3];
    lroot[l] = (const float*)d_in[8 + 6*l + 4];
    lbias[l] = (const float*)d_in[8 + 6*l + 5];
  }
  const float* emW1  = (const float*)d_in[26];
  const float* emb1  = (const float*)d_in[27];
  const float* emW2  = (const float*)d_in[28];
  const float* emb2  = (const float*)d_in[29];
  const float* nm1W1 = (const float*)d_in[30];
  const float* nm1b1 = (const float*)d_in[31];
  const float* nm1W2 = (const float*)d_in[32];
  const float* nm1b2 = (const float*)d_in[33];
  const float* nm2W1 = (const float*)d_in[34];
  const float* nm2b1 = (const float*)d_in[35];
  const float* nm2W2 = (const float*)d_in[36];
  const float* nm2b2 = (const float*)d_in[37];

  const int* rowp = ei;
  const int* colp = ei + NE;

  // workspace layout (float units)
  float* ws   = (float*)d_ws;
  float* x_a  = ws;                                 // NN*32
  float* x_b  = x_a + (size_t)NN*HD;                // NN*32
  float* scr  = x_b + (size_t)NN*HD;                // 16384 floats
  float* partial_e = scr;            // 5120
  float* partial_x = scr + 5120;     // 2048
  float* ss_g      = scr + 7168;     // 70
  float* W1f       = scr + 7424;     // 1920
  float* b1f       = scr + 9344;     // 96
  float* biasP     = scr + 9440;     // 128
  short* w2pk   = (short*)(scr + 16384);            // 3*32768 shorts
  short* predpk = w2pk + 3*32768;                   // 8192 shorts
  short* T10    = predpk + 8192;                    // NE*32 bf16
  short* T11    = T10 + (size_t)NE*32;
  short* T12    = T11 + (size_t)NE*32;
  float* agg    = (float*)T10;                      // alias (T10 dead after layer-0 msg)
  float* cnt    = agg + (size_t)NN*HD;

  stats_all_kernel<<<NBLK_E + NBLK_X, 256, 0, stream>>>(e, x, partial_e, partial_x);
  prep_kernel<<<1, 1024, 0, stream>>>(partial_e, partial_x,
                                      bn_edge_g, bn_edge_b, bn_node_g, bn_node_b,
                                      lW1[0], lb1[0], lW1[1], lb1[1], lW1[2], lb1[2],
                                      emW1, emb1, emW2, emb2,
                                      nm1W1, nm1b1, nm1W2, nm1b2,
                                      ss_g, W1f, b1f, biasP, predpk);
  w2pack_all_kernel<<<320, 256, 0, stream>>>(lW2[0], lW2[1], lW2[2], w2pk);
  t1all_kernel<<<(NE + 255)/256, 256, 0, stream>>>(e, W1f, b1f, T10, T11, T12);

  const int nblocks  = (NN + 255)/256;          // 196
  const int m8blocks = (NTILES + 3)/4;          // 2344 (2 tiles/block x TPW=2)

  // layer 0 (din=16): rootn (BN in regs) -> x_a ; msg reads raw x + folds BN on load
  rootn_kernel<<<nblocks, 256, 0, stream>>>(x, ss_g + 2*EIN, lroot[0], lbias[0], x_a);
  msg8_kernel<NIN, 32, 2, 1><<<m8blocks, 256, 0, stream>>>(T10, rowp, colp, x,
                                                           ss_g + 2*EIN,
                                                           w2pk + 0*32768, lb2[0], x_a);
  // layer 1 (din=32): x_a -> x_b
  rootv2_kernel<HD><<<nblocks, 256, 0, stream>>>(x_a, lroot[1], lbias[1], x_b);
  msg8_kernel<HD, 64, 2, 0><<<m8blocks, 256, 0, stream>>>(T11, rowp, colp, x_a,
                                                          nullptr,
                                                          w2pk + 1*32768, lb2[1], x_b);
  // layer 2 (din=32): x_b -> x_a
  rootv2_kernel<HD><<<nblocks, 256, 0, stream>>>(x_b, lroot[2], lbias[2], x_a);
  msg8_kernel<HD, 64, 2, 0><<<m8blocks, 256, 0, stream>>>(T12, rowp, colp, x_b,
                                                          nullptr,
                                                          w2pk + 2*32768, lb2[2], x_a);

  // predictor (agg/cnt alias T10 — zero with fast kernel)
  zero_kernel<<<2048, 256, 0, stream>>>(agg, NN*HD + NN);
  pred6_kernel<<<(NTILES + 7)/8, 256, 0, stream>>>(x_a, e, rowp, colp, predpk, biasP, agg, cnt);
  final2_kernel<<<(NN + 255)/256, 256, 0, stream>>>(x_a, agg, cnt,
                                                    nm2W1, nm2b1, nm2W2, nm2b2,
                                                    (float*)d_out);
}

// Round 13
// 219.475 us; speedup vs baseline: 1.1070x; 1.1070x over previous
//
#include <hip/hip_runtime.h>
#include <math.h>

constexpr int NN  = 50000;   // nodes
constexpr int NE  = 150000;  // edges
constexpr int NIN = 16;      // node features in
constexpr int EIN = 19;      // edge features in
constexpr int HD  = 32;      // hidden H
constexpr int NTILES = NE / 16;  // 9375
constexpr int NBLK_E = 128;
constexpr int NBLK_X = 64;

#define LEAK  0.1f
#define BNEPS 1e-5f

typedef __attribute__((ext_vector_type(8))) short bfrag;
typedef __attribute__((ext_vector_type(4))) float f32x4;
typedef __attribute__((ext_vector_type(2))) float f32x2;
typedef __attribute__((ext_vector_type(4))) int   i32x4;

__device__ __forceinline__ float lky(float v){ return fmaxf(v, LEAK*v); }
__device__ __forceinline__ unsigned f2bf(float f){
  unsigned u = __float_as_uint(f);
  return ((u + 0x7FFFu + ((u >> 16) & 1u)) >> 16);   // RNE
}
__device__ __forceinline__ void split8(const float* v, i32x4& h4, i32x4& l4){
  unsigned hs[8], ls[8];
  #pragma unroll
  for(int j = 0; j < 8; j++){
    unsigned hh = f2bf(v[j]);
    float hf = __uint_as_float(hh << 16);
    hs[j] = hh; ls[j] = f2bf(v[j] - hf);
  }
  h4[0] = (int)(hs[0] | (hs[1]<<16)); h4[1] = (int)(hs[2] | (hs[3]<<16));
  h4[2] = (int)(hs[4] | (hs[5]<<16)); h4[3] = (int)(hs[6] | (hs[7]<<16));
  l4[0] = (int)(ls[0] | (ls[1]<<16)); l4[1] = (int)(ls[2] | (ls[3]<<16));
  l4[2] = (int)(ls[4] | (ls[5]<<16)); l4[3] = (int)(ls[6] | (ls[7]<<16));
}

// ---------------------------------------------------------------- zero
__global__ void zero_kernel(float* __restrict__ p, int n){
  int stride = gridDim.x * blockDim.x;
  for(int i = blockIdx.x*blockDim.x + threadIdx.x; i < n; i += stride) p[i] = 0.f;
}

// ---------------------------------------------------------------- stats (proven R5)
__global__ __launch_bounds__(256) void stats_all_kernel(const float* __restrict__ e,
                                                        const float* __restrict__ x,
                                                        float* __restrict__ partial_e,
                                                        float* __restrict__ partial_x){
  __shared__ float red[4][40];
  const int tid = threadIdx.x, lane = tid & 63, wid = tid >> 6;
  if(blockIdx.x < NBLK_E){
    float s[EIN], q[EIN];
    #pragma unroll
    for(int c = 0; c < EIN; c++){ s[c] = 0.f; q[c] = 0.f; }
    const int gstride = NBLK_E * 256;
    for(int g = blockIdx.x*256 + tid; g < NE/4; g += gstride){
      const f32x4* p = (const f32x4*)(e + (size_t)g * 76);
      #pragma unroll
      for(int m = 0; m < 19; m++){
        f32x4 v = p[m];
        #pragma unroll
        for(int j = 0; j < 4; j++){
          int c = (4*m + j) % 19;
          s[c] += v[j]; q[c] = fmaf(v[j], v[j], q[c]);
        }
      }
    }
    #pragma unroll
    for(int off = 32; off; off >>= 1){
      #pragma unroll
      for(int c = 0; c < EIN; c++){ s[c] += __shfl_xor(s[c], off); q[c] += __shfl_xor(q[c], off); }
    }
    if(lane == 0){
      #pragma unroll
      for(int c = 0; c < EIN; c++){ red[wid][c] = s[c]; red[wid][20 + c] = q[c]; }
    }
    __syncthreads();
    if(tid < 39 && tid != 19)
      partial_e[blockIdx.x*40 + tid] = red[0][tid] + red[1][tid] + red[2][tid] + red[3][tid];
  } else {
    float s[NIN], q[NIN];
    #pragma unroll
    for(int c = 0; c < NIN; c++){ s[c] = 0.f; q[c] = 0.f; }
    const int bid = blockIdx.x - NBLK_E;
    const int gstride = NBLK_X * 256;
    for(int r = bid*256 + tid; r < NN; r += gstride){
      const f32x4* p = (const f32x4*)(x + (size_t)r * NIN);
      #pragma unroll
      for(int m = 0; m < 4; m++){
        f32x4 v = p[m];
        #pragma unroll
        for(int j = 0; j < 4; j++){
          int c = 4*m + j;
          s[c] += v[j]; q[c] = fmaf(v[j], v[j], q[c]);
        }
      }
    }
    #pragma unroll
    for(int off = 32; off; off >>= 1){
      #pragma unroll
      for(int c = 0; c < NIN; c++){ s[c] += __shfl_xor(s[c], off); q[c] += __shfl_xor(q[c], off); }
    }
    if(lane == 0){
      #pragma unroll
      for(int c = 0; c < NIN; c++){ red[wid][c] = s[c]; red[wid][16 + c] = q[c]; }
    }
    __syncthreads();
    if(tid < 32)
      partial_x[bid*32 + tid] = red[0][tid] + red[1][tid] + red[2][tid] + red[3][tid];
  }
}

// ---------------------------------------------------------------- prep (proven R5)
__global__ __launch_bounds__(1024) void prep_kernel(const float* __restrict__ partial_e,
                                                    const float* __restrict__ partial_x,
                                                    const float* __restrict__ ge, const float* __restrict__ be,
                                                    const float* __restrict__ gx, const float* __restrict__ bx,
                                                    const float* __restrict__ l0W1, const float* __restrict__ l0b1,
                                                    const float* __restrict__ l1W1, const float* __restrict__ l1b1,
                                                    const float* __restrict__ l2W1, const float* __restrict__ l2b1,
                                                    const float* __restrict__ emW1, const float* __restrict__ emb1,
                                                    const float* __restrict__ emW2, const float* __restrict__ emb2,
                                                    const float* __restrict__ nm1W1, const float* __restrict__ nm1b1,
                                                    const float* __restrict__ nm1W2, const float* __restrict__ nm1b2,
                                                    float* __restrict__ ss_g, float* __restrict__ W1f,
                                                    float* __restrict__ b1f, float* __restrict__ biasP,
                                                    short* __restrict__ predpk){
  __shared__ float ss[70];
  __shared__ float emW1f[608];
  __shared__ float emb1f[32];
  __shared__ float predW[7168];
  const int t = threadIdx.x;

  if(t < EIN){
    float s = 0.f, q = 0.f;
    for(int b = 0; b < NBLK_E; b++){ s += partial_e[b*40 + t]; q += partial_e[b*40 + 20 + t]; }
    float m = s / (float)NE;
    float v = q / (float)NE - m*m;
    float sc = ge[t] * rsqrtf(v + BNEPS);
    ss[t] = sc; ss[EIN + t] = be[t] - m*sc;
  } else if(t >= 32 && t < 32 + NIN){
    int c = t - 32;
    float s = 0.f, q = 0.f;
    for(int b = 0; b < NBLK_X; b++){ s += partial_x[b*32 + c]; q += partial_x[b*32 + 16 + c]; }
    float m = s / (float)NN;
    float v = q / (float)NN - m*m;
    float sc = gx[c] * rsqrtf(v + BNEPS);
    ss[2*EIN + c] = sc; ss[2*EIN + NIN + c] = bx[c] - m*sc;
  }
  __syncthreads();
  if(t < 70) ss_g[t] = ss[t];

  if(t < 128){
    int seg = t >> 5, j = t & 31;
    if(seg == 0){
      if(j < NIN){
        float acc = l0b1[j];
        for(int k = 0; k < EIN; k++){
          W1f[0*640 + k*NIN + j] = ss[k] * l0W1[k*NIN + j];
          acc += ss[EIN+k] * l0W1[k*NIN + j];
        }
        b1f[0*32 + j] = acc;
      }
    } else if(seg == 1){
      float acc = l1b1[j];
      for(int k = 0; k < EIN; k++){
        W1f[1*640 + k*HD + j] = ss[k] * l1W1[k*HD + j];
        acc += ss[EIN+k] * l1W1[k*HD + j];
      }
      b1f[1*32 + j] = acc;
    } else if(seg == 2){
      float acc = l2b1[j];
      for(int k = 0; k < EIN; k++){
        W1f[2*640 + k*HD + j] = ss[k] * l2W1[k*HD + j];
        acc += ss[EIN+k] * l2W1[k*HD + j];
      }
      b1f[2*32 + j] = acc;
    } else {
      float acc = emb1[j];
      for(int k = 0; k < EIN; k++){
        emW1f[k*HD + j] = ss[k] * emW1[(2*HD+k)*HD + j];
        acc += ss[EIN+k] * emW1[(2*HD+k)*HD + j];
      }
      emb1f[j] = acc;
    }
  }
  __syncthreads();

  for(int i = t; i < 224*32; i += 1024){
    int k = i >> 5, n = i & 31;
    float v;
    if(k < 64)       v = emW1[k*32 + n];
    else if(k < 83)  v = emW1f[(k-64)*32 + n];
    else if(k < 96)  v = 0.f;
    else if(k < 128) v = emW2[(k-96)*32 + n];
    else if(k < 192) v = nm1W1[(k-128)*32 + n];
    else             v = nm1W2[(k-192)*32 + n];
    predW[i] = v;
  }
  if(t < 128){
    int s = t >> 5, n = t & 31;
    biasP[t] = (s==0) ? emb1f[n] : (s==1) ? emb2[n] : (s==2) ? nm1b1[n] : nm1b2[n];
  }
  __syncthreads();

  for(int idx = t; idx < 14*512; idx += 1024){
    int c = idx >> 9, l = (idx >> 3) & 63, j = idx & 7;
    int kbg = c >> 1, nc = c & 1;
    int k = kbg*32 + 8*(l>>4) + j;
    int n = nc*16 + (l & 15);
    predpk[idx] = (short)f2bf(predW[k*32 + n]);
  }
}

// ---------------------------------------------------------------- pack all three W2
__global__ __launch_bounds__(256) void w2pack_all_kernel(const float* __restrict__ W20,
                                                         const float* __restrict__ W21,
                                                         const float* __restrict__ W22,
                                                         short* __restrict__ w2pk){
  int idx = blockIdx.x*256 + threadIdx.x;
  if(idx >= 81920) return;
  const float* W2; int DIN, base, ci;
  if(idx < 16384){ W2 = W20; DIN = 16; base = 0;     ci = idx; }
  else if(idx < 49152){ W2 = W21; DIN = 32; base = 32768; ci = idx - 16384; }
  else { W2 = W22; DIN = 32; base = 65536; ci = idx - 49152; }
  int c = ci >> 9, l = (ci >> 3) & 63, j = ci & 7;
  int k = 8*(l>>4) + j;
  int n = c*16 + (l & 15);
  float v = (k < DIN) ? W2[(size_t)k*(DIN*HD) + n] : 0.f;
  w2pk[base + ci] = (short)f2bf(v);
}

// ---------------------------------------------------------------- fused: BN-normalize(x) + layer0 root GEMV
__global__ __launch_bounds__(256) void norm_root_kernel(const float* __restrict__ x,
                                                        const float* __restrict__ ssx,
                                                        const float* __restrict__ root,
                                                        const float* __restrict__ bias,
                                                        float* __restrict__ x_bn,
                                                        float* __restrict__ x_a){
  __shared__ float rs[NIN*HD];
  __shared__ float scs[NIN], shs[NIN], bs[HD];
  const int tid = threadIdx.x;
  for(int i = tid; i < NIN*HD; i += 256) rs[i] = root[i];
  if(tid < NIN){ scs[tid] = ssx[tid]; shs[tid] = ssx[NIN + tid]; }
  else if(tid < NIN + HD) bs[tid - NIN] = bias[tid - NIN];
  __syncthreads();

  int n = blockIdx.x*256 + tid;
  if(n >= NN) return;
  float xb[NIN];
  const f32x4* xp = (const f32x4*)(x + (size_t)n*NIN);
  #pragma unroll
  for(int g = 0; g < 4; g++){
    f32x4 v = xp[g];
    #pragma unroll
    for(int j = 0; j < 4; j++) xb[g*4+j] = fmaf(v[j], scs[g*4+j], shs[g*4+j]);
  }
  f32x4* obn = (f32x4*)(x_bn + (size_t)n*NIN);
  #pragma unroll
  for(int g = 0; g < 4; g++){
    f32x4 v; v[0]=xb[g*4]; v[1]=xb[g*4+1]; v[2]=xb[g*4+2]; v[3]=xb[g*4+3];
    obn[g] = v;
  }
  f32x4 a0 = *(const f32x4*)&bs[0],  a1 = *(const f32x4*)&bs[4];
  f32x4 a2 = *(const f32x4*)&bs[8],  a3 = *(const f32x4*)&bs[12];
  f32x4 a4 = *(const f32x4*)&bs[16], a5 = *(const f32x4*)&bs[20];
  f32x4 a6 = *(const f32x4*)&bs[24], a7 = *(const f32x4*)&bs[28];
  #pragma unroll
  for(int k = 0; k < NIN; k++){
    float v = xb[k];
    const f32x4* wp = (const f32x4*)&rs[k*HD];
    a0 = __builtin_elementwise_fma((f32x4){v,v,v,v}, wp[0], a0);
    a1 = __builtin_elementwise_fma((f32x4){v,v,v,v}, wp[1], a1);
    a2 = __builtin_elementwise_fma((f32x4){v,v,v,v}, wp[2], a2);
    a3 = __builtin_elementwise_fma((f32x4){v,v,v,v}, wp[3], a3);
    a4 = __builtin_elementwise_fma((f32x4){v,v,v,v}, wp[4], a4);
    a5 = __builtin_elementwise_fma((f32x4){v,v,v,v}, wp[5], a5);
    a6 = __builtin_elementwise_fma((f32x4){v,v,v,v}, wp[6], a6);
    a7 = __builtin_elementwise_fma((f32x4){v,v,v,v}, wp[7], a7);
  }
  f32x4* outp = (f32x4*)(x_a + (size_t)n*HD);
  outp[0]=a0; outp[1]=a1; outp[2]=a2; outp[3]=a3;
  outp[4]=a4; outp[5]=a5; outp[6]=a6; outp[7]=a7;
}

// ---------------------------------------------------------------- T1 for ALL layers in one pass over e
__global__ __launch_bounds__(256) void t1all_kernel(const float* __restrict__ eraw,
                                                    const float* __restrict__ W1f,
                                                    const float* __restrict__ b1f,
                                                    short* __restrict__ T10,
                                                    short* __restrict__ T11,
                                                    short* __restrict__ T12){
  int e = blockIdx.x*256 + threadIdx.x;
  if(e >= NE) return;
  const float* ep = eraw + (size_t)e*EIN;
  float eb[EIN];
  #pragma unroll
  for(int k = 0; k < EIN; k++) eb[k] = ep[k];

  {
    float tv[16];
    #pragma unroll
    for(int j = 0; j < 16; j++) tv[j] = b1f[j];
    #pragma unroll
    for(int k = 0; k < EIN; k++){
      float v = eb[k];
      #pragma unroll
      for(int j = 0; j < 16; j++) tv[j] = fmaf(v, W1f[k*16 + j], tv[j]);
    }
    unsigned pk[8];
    #pragma unroll
    for(int p = 0; p < 8; p++){
      float a = tv[2*p], b = tv[2*p+1];
      pk[p] = f2bf(fmaxf(a, LEAK*a)) | (f2bf(fmaxf(b, LEAK*b)) << 16);
    }
    i32x4* outp = (i32x4*)(T10 + (size_t)e*32);
    i32x4 v0; v0[0]=(int)pk[0]; v0[1]=(int)pk[1]; v0[2]=(int)pk[2]; v0[3]=(int)pk[3];
    i32x4 v1; v1[0]=(int)pk[4]; v1[1]=(int)pk[5]; v1[2]=(int)pk[6]; v1[3]=(int)pk[7];
    i32x4 zz; zz[0]=0; zz[1]=0; zz[2]=0; zz[3]=0;
    outp[0] = v0; outp[1] = v1; outp[2] = zz; outp[3] = zz;
  }
  #pragma unroll
  for(int l = 1; l < 3; l++){
    const float* Wl = W1f + l*640;
    const float* bl = b1f + l*32;
    short* Tl = (l == 1) ? T11 : T12;
    float tv[32];
    #pragma unroll
    for(int j = 0; j < 32; j++) tv[j] = bl[j];
    #pragma unroll
    for(int k = 0; k < EIN; k++){
      float v = eb[k];
      #pragma unroll
      for(int j = 0; j < 32; j++) tv[j] = fmaf(v, Wl[k*32 + j], tv[j]);
    }
    unsigned pk[16];
    #pragma unroll
    for(int p = 0; p < 16; p++){
      float a = tv[2*p], b = tv[2*p+1];
      pk[p] = f2bf(fmaxf(a, LEAK*a)) | (f2bf(fmaxf(b, LEAK*b)) << 16);
    }
    i32x4* outp = (i32x4*)(Tl + (size_t)e*32);
    #pragma unroll
    for(int g = 0; g < 4; g++){
      i32x4 v; v[0]=(int)pk[g*4]; v[1]=(int)pk[g*4+1]; v[2]=(int)pk[g*4+2]; v[3]=(int)pk[g*4+3];
      outp[g] = v;
    }
  }
}

// ---------------------------------------------------------------- root (layers 1,2)
template<int DIN>
__global__ __launch_bounds__(256) void rootv2_kernel(const float* __restrict__ xin,
                                                     const float* __restrict__ root,
                                                     const float* __restrict__ bias,
                                                     float* __restrict__ xout){
  int n = blockIdx.x*256 + threadIdx.x;
  if(n >= NN) return;
  float xr[DIN];
  const f32x4* xp = (const f32x4*)(xin + (size_t)n*DIN);
  #pragma unroll
  for(int g = 0; g < DIN/4; g++){ f32x4 v = xp[g];
    #pragma unroll
    for(int j = 0; j < 4; j++) xr[g*4+j] = v[j]; }
  float acc[HD];
  #pragma unroll
  for(int o = 0; o < HD; o++) acc[o] = bias[o];
  #pragma unroll
  for(int k = 0; k < DIN; k++){
    float v = xr[k];
    #pragma unroll
    for(int o = 0; o < HD; o++) acc[o] = fmaf(v, root[k*HD + o], acc[o]);
  }
  f32x4* outp = (f32x4*)(xout + (size_t)n*HD);
  #pragma unroll
  for(int g = 0; g < 8; g++){ f32x4 v; v[0]=acc[g*4]; v[1]=acc[g*4+1]; v[2]=acc[g*4+2]; v[3]=acc[g*4+3]; outp[g] = v; }
}

// ---------------------------------------------------------------- msg v6 (proven best: R9 bench 219.9)
template<int DIN, int NCH, int HALVES>
__global__ __launch_bounds__(512) void msg6_kernel(const short* __restrict__ T1,
                                                   const int* __restrict__ rowp,
                                                   const int* __restrict__ colp,
                                                   const float* __restrict__ xin,
                                                   const short* __restrict__ w2p,
                                                   const float* __restrict__ b2,
                                                   float* __restrict__ xout){
  constexpr int CH = NCH / HALVES;
  __shared__ short w2s[CH*512];
  __shared__ float b2s[NCH*16];
  __shared__ float xgs[8][DIN][16];     // transposed: [i][edge]

  const int tid = threadIdx.x;
  const int l   = tid & 63;
  const int wid = tid >> 6;
  const int grp = l >> 4, lo16 = l & 15;
  const int tile = blockIdx.x*8 + wid;
  const bool active = tile < NTILES;
  const int e0 = tile * 16;

  if(active){
    int r = rowp[e0 + lo16];
    if(DIN == 32){
      const f32x4* xp = (const f32x4*)(xin + (size_t)r*32 + grp*8);
      f32x4 a = xp[0], b = xp[1];
      #pragma unroll
      for(int j = 0; j < 4; j++) xgs[wid][grp*8 + j][lo16]     = a[j];
      #pragma unroll
      for(int j = 0; j < 4; j++) xgs[wid][grp*8 + 4 + j][lo16] = b[j];
    } else {
      const f32x4* xp = (const f32x4*)(xin + (size_t)r*16 + grp*4);
      f32x4 a = xp[0];
      #pragma unroll
      for(int j = 0; j < 4; j++) xgs[wid][grp*4 + j][lo16] = a[j];
    }
  }

  bfrag af = {0,0,0,0,0,0,0,0};
  if(active) af = *(const bfrag*)(T1 + (size_t)(e0 + lo16)*32 + grp*8);

  f32x2 m0a = {0.f,0.f}, m0b = {0.f,0.f}, m1a = {0.f,0.f}, m1b = {0.f,0.f};

  for(int h = 0; h < HALVES; h++){
    if(h) __syncthreads();
    for(int t = tid; t < CH*64; t += 512)
      ((i32x4*)w2s)[t] = ((const i32x4*)w2p)[h*CH*64 + t];
    if(h == 0)
      for(int t = tid; t < NCH*16; t += 512) b2s[t] = b2[t];
    __syncthreads();

    if(active){
      #pragma unroll 4
      for(int i = 0; i < CH/2; i++){
        const int cg = h*CH + 2*i;
        const int ig = cg >> 1;
        float bv0 = b2s[cg*16 + lo16];
        float bv1 = b2s[(cg+1)*16 + lo16];
        f32x4 c0 = {bv0,bv0,bv0,bv0};
        f32x4 c1 = {bv1,bv1,bv1,bv1};
        bfrag b0 = *(const bfrag*)&w2s[((2*i  )*64 + l)*8];
        bfrag b1 = *(const bfrag*)&w2s[((2*i+1)*64 + l)*8];
        f32x4 u0 = __builtin_amdgcn_mfma_f32_16x16x32_bf16(af, b0, c0, 0, 0, 0);
        f32x4 u1 = __builtin_amdgcn_mfma_f32_16x16x32_bf16(af, b1, c1, 0, 0, 0);

        f32x4 xv = *(const f32x4*)&xgs[wid][ig][grp*4];
        f32x2 xva = {xv[0], xv[1]}, xvb = {xv[2], xv[3]};
        f32x2 u0a = {u0[0],u0[1]}, u0b = {u0[2],u0[3]};
        f32x2 u1a = {u1[0],u1[1]}, u1b = {u1[2],u1[3]};
        f32x2 a0a = __builtin_elementwise_max(u0a, u0a*LEAK);
        f32x2 a0b = __builtin_elementwise_max(u0b, u0b*LEAK);
        f32x2 a1a = __builtin_elementwise_max(u1a, u1a*LEAK);
        f32x2 a1b = __builtin_elementwise_max(u1b, u1b*LEAK);
        m0a = __builtin_elementwise_fma(xva, a0a, m0a);
        m0b = __builtin_elementwise_fma(xvb, a0b, m0b);
        m1a = __builtin_elementwise_fma(xva, a1a, m1a);
        m1b = __builtin_elementwise_fma(xvb, a1b, m1b);
      }
    }
  }

  if(active){
    float m0[4] = {m0a[0], m0a[1], m0b[0], m0b[1]};
    float m1[4] = {m1a[0], m1a[1], m1b[0], m1b[1]};
    #pragma unroll
    for(int reg = 0; reg < 4; reg++){
      int ce = colp[e0 + grp*4 + reg];
      atomicAdd(&xout[(size_t)ce*HD + lo16],      m0[reg]);
      atomicAdd(&xout[(size_t)ce*HD + 16 + lo16], m1[reg]);
    }
  }
}

// ---------------------------------------------------------------- predictor v5 (proven best config, TPW=4)
__global__ __launch_bounds__(256, 4) void pred5_kernel(const float* __restrict__ x,
                                                       const float* __restrict__ eraw,
                                                       const int* __restrict__ rowp,
                                                       const int* __restrict__ colp,
                                                       const short* __restrict__ predpk,
                                                       const float* __restrict__ biasP,
                                                       float* __restrict__ agg,
                                                       float* __restrict__ cnt){
  __shared__ short fAhi[4][16][104];
  __shared__ short fAlo[4][16][104];
  __shared__ short uAhi[4][16][40];
  __shared__ short uAlo[4][16][40];

  const int tid = threadIdx.x;
  const int l = tid & 63, wid = tid >> 6;
  const int grp = l >> 4, lo16 = l & 15;

  bfrag wb[14];
  #pragma unroll
  for(int c = 0; c < 14; c++) wb[c] = *(const bfrag*)(predpk + ((size_t)c*64 + l)*8);
  float bP[8];
  #pragma unroll
  for(int s = 0; s < 4; s++){
    bP[s*2]   = biasP[s*32 + lo16];
    bP[s*2+1] = biasP[s*32 + 16 + lo16];
  }

  f32x4 z; z[0]=0.f; z[1]=0.f; z[2]=0.f; z[3]=0.f;
  const int tbase = (blockIdx.x*4 + wid) * 4;

  for(int tt = 0; tt < 4; tt++){
    const int tile = tbase + tt;
    if(tile >= NTILES) break;
    const int e0 = tile * 16;

    {
      float v[8];
      i32x4 h4, l4;
      int r = rowp[e0 + lo16];
      const float* xp = x + (size_t)r*32 + grp*8;
      #pragma unroll
      for(int j = 0; j < 8; j++) v[j] = xp[j];
      split8(v, h4, l4);
      *(i32x4*)&fAhi[wid][lo16][grp*8] = h4;
      *(i32x4*)&fAlo[wid][lo16][grp*8] = l4;

      int c = colp[e0 + lo16];
      const float* xq = x + (size_t)c*32 + grp*8;
      #pragma unroll
      for(int j = 0; j < 8; j++) v[j] = xq[j];
      split8(v, h4, l4);
      *(i32x4*)&fAhi[wid][lo16][32 + grp*8] = h4;
      *(i32x4*)&fAlo[wid][lo16][32 + grp*8] = l4;

      const float* ep = eraw + (size_t)(e0 + lo16)*EIN;
      #pragma unroll
      for(int j = 0; j < 8; j++){ int f = grp*8 + j; v[j] = (f < EIN) ? ep[f] : 0.f; }
      split8(v, h4, l4);
      *(i32x4*)&fAhi[wid][lo16][64 + grp*8] = h4;
      *(i32x4*)&fAlo[wid][lo16][64 + grp*8] = l4;
    }

    #pragma unroll
    for(int nc = 0; nc < 2; nc++){
      f32x4 acc = z;
      #pragma unroll
      for(int kb = 0; kb < 3; kb++){
        bfrag ah = *(const bfrag*)&fAhi[wid][lo16][kb*32 + grp*8];
        bfrag al = *(const bfrag*)&fAlo[wid][lo16][kb*32 + grp*8];
        acc = __builtin_amdgcn_mfma_f32_16x16x32_bf16(ah, wb[kb*2 + nc], acc, 0, 0, 0);
        acc = __builtin_amdgcn_mfma_f32_16x16x32_bf16(al, wb[kb*2 + nc], acc, 0, 0, 0);
      }
      int n = nc*16 + lo16;
      float bv = bP[nc];
      #pragma unroll
      for(int reg = 0; reg < 4; reg++){
        float uv = acc[reg] + bv; uv = fmaxf(uv, LEAK*uv);
        unsigned hh = f2bf(uv);
        float hf = __uint_as_float(hh << 16);
        uAhi[wid][grp*4 + reg][n] = (short)hh;
        uAlo[wid][grp*4 + reg][n] = (short)f2bf(uv - hf);
      }
    }

    #pragma unroll
    for(int nc = 0; nc < 2; nc++){
      f32x4 acc = z;
      bfrag ah = *(const bfrag*)&uAhi[wid][lo16][grp*8];
      bfrag al = *(const bfrag*)&uAlo[wid][lo16][grp*8];
      acc = __builtin_amdgcn_mfma_f32_16x16x32_bf16(ah, wb[6 + nc], acc, 0, 0, 0);
      acc = __builtin_amdgcn_mfma_f32_16x16x32_bf16(al, wb[6 + nc], acc, 0, 0, 0);
      int n = nc*16 + lo16;
      float bv = bP[2 + nc];
      #pragma unroll
      for(int reg = 0; reg < 4; reg++){
        float ev = acc[reg] + bv;
        unsigned hh = f2bf(ev);
        float hf = __uint_as_float(hh << 16);
        fAhi[wid][grp*4 + reg][32 + n] = (short)hh;
        fAlo[wid][grp*4 + reg][32 + n] = (short)f2bf(ev - hf);
      }
    }

    #pragma unroll
    for(int nc = 0; nc < 2; nc++){
      f32x4 acc = z;
      #pragma unroll
      for(int kb = 0; kb < 2; kb++){
        bfrag ah = *(const bfrag*)&fAhi[wid][lo16][kb*32 + grp*8];
        bfrag al = *(const bfrag*)&fAlo[wid][lo16][kb*32 + grp*8];
        acc = __builtin_amdgcn_mfma_f32_16x16x32_bf16(ah, wb[8 + kb*2 + nc], acc, 0, 0, 0);
        acc = __builtin_amdgcn_mfma_f32_16x16x32_bf16(al, wb[8 + kb*2 + nc], acc, 0, 0, 0);
      }
      int n = nc*16 + lo16;
      float bv = bP[4 + nc];
      #pragma unroll
      for(int reg = 0; reg < 4; reg++){
        float vv = acc[reg] + bv; vv = fmaxf(vv, LEAK*vv);
        unsigned hh = f2bf(vv);
        float hf = __uint_as_float(hh << 16);
        uAhi[wid][grp*4 + reg][n] = (short)hh;
        uAlo[wid][grp*4 + reg][n] = (short)f2bf(vv - hf);
      }
    }

    int ce[4];
    #pragma unroll
    for(int reg = 0; reg < 4; reg++) ce[reg] = colp[e0 + grp*4 + reg];

    #pragma unroll
    for(int nc = 0; nc < 2; nc++){
      f32x4 acc = z;
      bfrag ah = *(const bfrag*)&uAhi[wid][lo16][grp*8];
      bfrag al = *(const bfrag*)&uAlo[wid][lo16][grp*8];
      acc = __builtin_amdgcn_mfma_f32_16x16x32_bf16(ah, wb[12 + nc], acc, 0, 0, 0);
      acc = __builtin_amdgcn_mfma_f32_16x16x32_bf16(al, wb[12 + nc], acc, 0, 0, 0);
      int n = nc*16 + lo16;
      float bv = bP[6 + nc];
      #pragma unroll
      for(int reg = 0; reg < 4; reg++)
        atomicAdd(&agg[(size_t)ce[reg]*HD + n], acc[reg] + bv);
    }

    if(l < 16) atomicAdd(&cnt[colp[e0 + l]], 1.f);
  }
}

// ---------------------------------------------------------------- final v2 (proven R8)
__global__ __launch_bounds__(256) void final2_kernel(const float* __restrict__ x,
                                                     const float* __restrict__ agg,
                                                     const float* __restrict__ cnt,
                                                     const float* __restrict__ W1,
                                                     const float* __restrict__ b1,
                                                     const float* __restrict__ W2,
                                                     const float* __restrict__ b2,
                                                     float* __restrict__ out){
  __shared__ float w1s[2*HD*HD];
  __shared__ float w2s[HD*2];
  __shared__ float b1s[HD];
  __shared__ float b2s[2];
  const int tid = threadIdx.x;
  for(int i = tid; i < 2*HD*HD; i += 256) w1s[i] = W1[i];
  if(tid < 64) w2s[tid] = W2[tid];
  if(tid < HD) b1s[tid] = b1[tid];
  if(tid < 2)  b2s[tid] = b2[tid];
  __syncthreads();

  int n = blockIdx.x*256 + tid;
  if(n >= NN) return;
  float inv = 1.f / fmaxf(cnt[n], 1.f);

  float xin[HD], ain[HD];
  const f32x4* xp = (const f32x4*)(x + (size_t)n*HD);
  const f32x4* ap = (const f32x4*)(agg + (size_t)n*HD);
  #pragma unroll
  for(int g = 0; g < 8; g++){
    f32x4 v = xp[g];
    #pragma unroll
    for(int j = 0; j < 4; j++) xin[g*4+j] = v[j];
  }
  #pragma unroll
  for(int g = 0; g < 8; g++){
    f32x4 v = ap[g];
    #pragma unroll
    for(int j = 0; j < 4; j++) ain[g*4+j] = v[j] * inv;
  }

  f32x4 a0 = *(const f32x4*)&b1s[0],  a1 = *(const f32x4*)&b1s[4];
  f32x4 a2 = *(const f32x4*)&b1s[8],  a3 = *(const f32x4*)&b1s[12];
  f32x4 a4 = *(const f32x4*)&b1s[16], a5 = *(const f32x4*)&b1s[20];
  f32x4 a6 = *(const f32x4*)&b1s[24], a7 = *(const f32x4*)&b1s[28];
  #pragma unroll
  for(int k = 0; k < HD; k++){
    float v = xin[k];
    const f32x4* wp = (const f32x4*)&w1s[k*HD];
    f32x4 vv = {v,v,v,v};
    a0 = __builtin_elementwise_fma(vv, wp[0], a0);
    a1 = __builtin_elementwise_fma(vv, wp[1], a1);
    a2 = __builtin_elementwise_fma(vv, wp[2], a2);
    a3 = __builtin_elementwise_fma(vv, wp[3], a3);
    a4 = __builtin_elementwise_fma(vv, wp[4], a4);
    a5 = __builtin_elementwise_fma(vv, wp[5], a5);
    a6 = __builtin_elementwise_fma(vv, wp[6], a6);
    a7 = __builtin_elementwise_fma(vv, wp[7], a7);
  }
  #pragma unroll
  for(int k = 0; k < HD; k++){
    float v = ain[k];
    const f32x4* wp = (const f32x4*)&w1s[(HD+k)*HD];
    f32x4 vv = {v,v,v,v};
    a0 = __builtin_elementwise_fma(vv, wp[0], a0);
    a1 = __builtin_elementwise_fma(vv, wp[1], a1);
    a2 = __builtin_elementwise_fma(vv, wp[2], a2);
    a3 = __builtin_elementwise_fma(vv, wp[3], a3);
    a4 = __builtin_elementwise_fma(vv, wp[4], a4);
    a5 = __builtin_elementwise_fma(vv, wp[5], a5);
    a6 = __builtin_elementwise_fma(vv, wp[6], a6);
    a7 = __builtin_elementwise_fma(vv, wp[7], a7);
  }

  float t[HD];
  *(f32x4*)&t[0]  = a0; *(f32x4*)&t[4]  = a1; *(f32x4*)&t[8]  = a2; *(f32x4*)&t[12] = a3;
  *(f32x4*)&t[16] = a4; *(f32x4*)&t[20] = a5; *(f32x4*)&t[24] = a6; *(f32x4*)&t[28] = a7;

  float o0 = b2s[0], o1 = b2s[1];
  #pragma unroll
  for(int k = 0; k < HD; k++){
    float v = lky(t[k]);
    o0 = fmaf(v, w2s[k*2],   o0);
    o1 = fmaf(v, w2s[k*2+1], o1);
  }

  float m  = fmaxf(o0, o1);
  float ls = m + logf(expf(o0 - m) + expf(o1 - m));
  out[(size_t)n*2]   = o0 - ls;
  out[(size_t)n*2+1] = o1 - ls;
}

// ---------------------------------------------------------------- launch
extern "C" void kernel_launch(void* const* d_in, const int* in_sizes, int n_in,
                              void* d_out, int out_size, void* d_ws, size_t ws_size,
                              hipStream_t stream){
  const float* x  = (const float*)d_in[0];
  const int*   ei = (const int*)  d_in[1];
  const float* e  = (const float*)d_in[2];
  const float* bn_node_g = (const float*)d_in[4];
  const float* bn_node_b = (const float*)d_in[5];
  const float* bn_edge_g = (const float*)d_in[6];
  const float* bn_edge_b = (const float*)d_in[7];
  const float* lW1[3], *lb1[3], *lW2[3], *lb2[3], *lroot[3], *lbias[3];
  for(int l = 0; l < 3; l++){
    lW1[l]   = (const float*)d_in[8 + 6*l + 0];
    lb1[l]   = (const float*)d_in[8 + 6*l + 1];
    lW2[l]   = (const float*)d_in[8 + 6*l + 2];
    lb2[l]   = (const float*)d_in[8 + 6*l + 3];
    lroot[l] = (const float*)d_in[8 + 6*l + 4];
    lbias[l] = (const float*)d_in[8 + 6*l + 5];
  }
  const float* emW1  = (const float*)d_in[26];
  const float* emb1  = (const float*)d_in[27];
  const float* emW2  = (const float*)d_in[28];
  const float* emb2  = (const float*)d_in[29];
  const float* nm1W1 = (const float*)d_in[30];
  const float* nm1b1 = (const float*)d_in[31];
  const float* nm1W2 = (const float*)d_in[32];
  const float* nm1b2 = (const float*)d_in[33];
  const float* nm2W1 = (const float*)d_in[34];
  const float* nm2b1 = (const float*)d_in[35];
  const float* nm2W2 = (const float*)d_in[36];
  const float* nm2b2 = (const float*)d_in[37];

  const int* rowp = ei;
  const int* colp = ei + NE;

  // workspace layout (float units)
  float* ws   = (float*)d_ws;
  float* x_bn = ws;                                 // NN*16
  float* x_a  = x_bn + (size_t)NN*NIN;              // NN*32
  float* x_b  = x_a  + (size_t)NN*HD;               // NN*32
  float* scr  = x_b  + (size_t)NN*HD;               // 16384 floats
  float* partial_e = scr;            // 5120
  float* partial_x = scr + 5120;     // 2048
  float* ss_g      = scr + 7168;     // 70
  float* W1f       = scr + 7424;     // 1920
  float* b1f       = scr + 9344;     // 96
  float* biasP     = scr + 9440;     // 128
  short* w2pk   = (short*)(scr + 16384);            // 3*32768 shorts
  short* predpk = w2pk + 3*32768;                   // 8192 shorts
  short* T10    = predpk + 8192;                    // NE*32 bf16
  short* T11    = T10 + (size_t)NE*32;
  short* T12    = T11 + (size_t)NE*32;
  float* agg    = (float*)T10;                      // alias (T10 dead after layer-0 msg)
  float* cnt    = agg + (size_t)NN*HD;

  stats_all_kernel<<<NBLK_E + NBLK_X, 256, 0, stream>>>(e, x, partial_e, partial_x);
  prep_kernel<<<1, 1024, 0, stream>>>(partial_e, partial_x,
                                      bn_edge_g, bn_edge_b, bn_node_g, bn_node_b,
                                      lW1[0], lb1[0], lW1[1], lb1[1], lW1[2], lb1[2],
                                      emW1, emb1, emW2, emb2,
                                      nm1W1, nm1b1, nm1W2, nm1b2,
                                      ss_g, W1f, b1f, biasP, predpk);
  w2pack_all_kernel<<<320, 256, 0, stream>>>(lW2[0], lW2[1], lW2[2], w2pk);
  t1all_kernel<<<(NE + 255)/256, 256, 0, stream>>>(e, W1f, b1f, T10, T11, T12);

  const int nblocks  = (NN + 255)/256;     // 196
  const int m6blocks = (NTILES + 7)/8;     // 1172

  // layer 0 (din=16): fused normalize+root -> x_bn, x_a
  norm_root_kernel<<<nblocks, 256, 0, stream>>>(x, ss_g + 2*EIN, lroot[0], lbias[0], x_bn, x_a);
  msg6_kernel<NIN, 32, 2><<<m6blocks, 512, 0, stream>>>(T10, rowp, colp, x_bn,
                                                        w2pk + 0*32768, lb2[0], x_a);
  // layer 1 (din=32): x_a -> x_b
  rootv2_kernel<HD><<<nblocks, 256, 0, stream>>>(x_a, lroot[1], lbias[1], x_b);
  msg6_kernel<HD, 64, 2><<<m6blocks, 512, 0, stream>>>(T11, rowp, colp, x_a,
                                                       w2pk + 1*32768, lb2[1], x_b);
  // layer 2 (din=32): x_b -> x_a
  rootv2_kernel<HD><<<nblocks, 256, 0, stream>>>(x_b, lroot[2], lbias[2], x_a);
  msg6_kernel<HD, 64, 2><<<m6blocks, 512, 0, stream>>>(T12, rowp, colp, x_b,
                                                       w2pk + 2*32768, lb2[2], x_a);

  // predictor (agg/cnt alias T10 — zero first)
  zero_kernel<<<2048, 256, 0, stream>>>(agg, NN*HD + NN);
  pred5_kernel<<<(NTILES + 15)/16, 256, 0, stream>>>(x_a, e, rowp, colp, predpk, biasP, agg, cnt);
  final2_kernel<<<(NN + 255)/256, 256, 0, stream>>>(x_a, agg, cnt,
                                                    nm2W1, nm2b1, nm2W2, nm2b2,
                                                    (float*)d_out);
}